// Round 4
// baseline (309.251 us; speedup 1.0000x reference)
//
#include <hip/hip_runtime.h>
#include <math.h>

#define NPTS    131072
#define PPB     32            // points per block
#define THREADS 256           // 4 waves (2x2 wave grid)
#define NBLK    (NPTS / PPB)  // 4096
#define HOFF    (7 * 16384)   // head-weight offset in wsW (bf16 elems)

typedef __attribute__((ext_vector_type(8))) short short8;
typedef __attribute__((ext_vector_type(4))) float f32x4;

__device__ __forceinline__ unsigned short f2bf(float f) {
  unsigned u = __float_as_uint(f);
  unsigned r = (u + 0x7fffu + ((u >> 16) & 1u)) >> 16;
  return (unsigned short)r;
}
#if defined(__has_builtin)
#if __has_builtin(__builtin_amdgcn_cvt_pk_bf16_f32)
#define HAVE_PK_BF16 1
#endif
#endif
__device__ __forceinline__ unsigned pk2(float lo, float hi) {
#ifdef HAVE_PK_BF16
  auto v = __builtin_amdgcn_cvt_pk_bf16_f32(lo, hi);
  unsigned u; __builtin_memcpy(&u, &v, 4); return u;
#else
  return (unsigned)f2bf(lo) | ((unsigned)f2bf(hi) << 16);
#endif
}
__device__ __forceinline__ void cross3(const float a[3], const float b[3], float o[3]) {
  o[0] = a[1]*b[2] - a[2]*b[1];
  o[1] = a[2]*b[0] - a[0]*b[2];
  o[2] = a[0]*b[1] - a[1]*b[0];
}
__device__ __forceinline__ float dot3(const float a[3], const float b[3]) {
  return a[0]*b[0] + a[1]*b[1] + a[2]*b[2];
}

// select via wave-uniform sgpr-pair mask: r = bit[lane](m) ? a : f
__device__ __forceinline__ float selmask(unsigned long long m, float a, float f) {
  float r;
  asm("v_cndmask_b32 %0, %1, %2, %3" : "=v"(r) : "v"(f), "v"(a), "s"(m));
  return r;
}

// sA element (r,k) lives at r*128 + ((k>>3)^(r&15))*8 + (k&7)   (XOR chunk swizzle)
__device__ __forceinline__ void swrite(unsigned short* sA, int r, int k, float v) {
  int off = r * 128 + ((((k >> 3) ^ (r & 15))) << 3) + (k & 7);
  sA[off] = f2bf(v);
}

// ---- weights -> bf16 workspace: 7x[128cols][128k] MLP + 16x128 heads ----
__global__ void convert_weights(const float* __restrict__ W_in,
                                const float* __restrict__ Ws,
                                const float* __restrict__ Ww,
                                const float* __restrict__ Wv,
                                unsigned short* __restrict__ wsW) {
  int idx = blockIdx.x * 256 + threadIdx.x;
  if (idx >= HOFF + 2048) return;
  float v;
  if (idx < HOFF) {
    int l = idx >> 14, r = idx & 16383, c = r >> 7, k = r & 127;
    if (l == 0) v = (k < 39) ? W_in[c * 39 + k] : 0.0f;
    else        v = Ws[(l - 1) * 16384 + c * 128 + k];
  } else {
    int r = idx - HOFF, o = r >> 7, k = r & 127;
    v = (o < 3) ? Ww[o * 128 + k] : (o < 6) ? Wv[(o - 3) * 128 + k] : 0.0f;
  }
  wsW[idx] = f2bf(v);
}

// One MLP layer. A-operand = weights from GLOBAL (L2-resident, register
// double-buffered + cross-layer prefetch); B-operand = acts from LDS.
// wf carries ks=0 weight frags in (this layer) and out (next layer).
template <int KMAX, bool LEAKY, bool HASNEXT>
__device__ __forceinline__ void layer_pass(unsigned short* __restrict__ sA,
                                           const float* __restrict__ bg,
                                           const unsigned short* __restrict__ W,
                                           const unsigned short* __restrict__ nextW,
                                           short8 (&wf)[4],
                                           int n16, int quad, int wr, int wc,
                                           int woff) {
  const bool isv = (n16 & 3) == 0;
  f32x4 ib[4];
  #pragma unroll
  for (int ct = 0; ct < 4; ++ct) {
    float4 b = *(const float4*)(bg + wc * 64 + ct * 16 + quad * 4);
    ib[ct][0] = isv ? b.x : 0.0f;
    ib[ct][1] = isv ? b.y : 0.0f;
    ib[ct][2] = isv ? b.z : 0.0f;
    ib[ct][3] = isv ? b.w : 0.0f;
  }

  const unsigned short* pA = sA + (wr * 64 + n16) * 128;
  f32x4 acc[4][4];
  short8 cur[4], nxt[4];
  #pragma unroll
  for (int ct = 0; ct < 4; ++ct) cur[ct] = wf[ct];

  #pragma unroll
  for (int ks = 0; ks < KMAX; ++ks) {
    if (ks + 1 < KMAX) {
      #pragma unroll
      for (int ct = 0; ct < 4; ++ct)
        nxt[ct] = *(const short8*)(W + woff + ct * 2048 + (ks + 1) * 32);
    } else if (HASNEXT) {
      #pragma unroll
      for (int ct = 0; ct < 4; ++ct)
        nxt[ct] = *(const short8*)(nextW + woff + ct * 2048);
    }
    short8 bx[4];
    const int ch = ((quad + 4 * ks) ^ n16) << 3;
    #pragma unroll
    for (int rt = 0; rt < 4; ++rt)
      bx[rt] = *(const short8*)(pA + rt * 2048 + ch);
    #pragma unroll
    for (int rt = 0; rt < 4; ++rt)
      #pragma unroll
      for (int ct = 0; ct < 4; ++ct)
        acc[rt][ct] = __builtin_amdgcn_mfma_f32_16x16x32_bf16(
            cur[ct], bx[rt], (ks == 0) ? ib[ct] : acc[rt][ct], 0, 0, 0);
    #pragma unroll
    for (int ct = 0; ct < 4; ++ct) cur[ct] = nxt[ct];
  }
  if (HASNEXT) {
    #pragma unroll
    for (int ct = 0; ct < 4; ++ct) wf[ct] = cur[ct];
  }

  // activation: ballot -> SALU expand (value-lane bit -> its 4-lane group) -> cndmask
  #pragma unroll
  for (int rt = 0; rt < 4; ++rt)
    #pragma unroll
    for (int ct = 0; ct < 4; ++ct)
      #pragma unroll
      for (int e = 0; e < 4; ++e) {
        float a = acc[rt][ct][e];
        unsigned long long m =
            (__ballot(a > 0.0f) & 0x1111111111111111ULL) * 15ULL;
        float f = LEAKY ? a * 0.01f : 0.0f;
        acc[rt][ct][e] = selmask(m, a, f);
      }

  __syncthreads();   // all waves done reading sA

  // packed C-writeback: 4 consecutive cols per lane -> one ds_write_b64
  #pragma unroll
  for (int rt = 0; rt < 4; ++rt) {
    int r = wr * 64 + rt * 16 + n16;
    #pragma unroll
    for (int ct = 0; ct < 4; ++ct) {
      int kc = wc * 8 + ct * 2 + (quad >> 1);
      int off = r * 128 + ((kc ^ n16) << 3) + (quad & 1) * 4;
      unsigned lo = pk2(acc[rt][ct][0], acc[rt][ct][1]);
      unsigned hi = pk2(acc[rt][ct][2], acc[rt][ct][3]);
      *(uint2*)(sA + off) = make_uint2(lo, hi);
    }
  }
  __syncthreads();   // sA(l+1) ready
}

__global__ __launch_bounds__(THREADS, 3)
void nerfies_mfma(const float* __restrict__ x,
                  const float* __restrict__ b_in,
                  const float* __restrict__ bs,
                  const float* __restrict__ bw,
                  const float* __restrict__ bv,
                  const unsigned short* __restrict__ wsW,
                  const int* __restrict__ iterp,
                  float* __restrict__ out)
{
  __shared__ __align__(16) unsigned short sA[128 * 128];  // 32 KB acts (swizzled)
  __shared__ __align__(16) float sH[128 * 16];            // 8 KB head outs
  __shared__ __align__(16) float sX[PPB * 3];

  const int tid  = threadIdx.x;
  const int lane = tid & 63;
  const int wv   = tid >> 6;
  const int n16  = lane & 15;
  const int quad = lane >> 4;
  const int wr   = wv >> 1;
  const int wc   = wv & 1;
  const int p0   = blockIdx.x * PPB;
  const int woff = (wc * 64 + n16) * 128 + quad * 8;

  // prologue: prefetch layer-0 ks0 weight frags, zero sA, load coords
  short8 wf[4];
  #pragma unroll
  for (int ct = 0; ct < 4; ++ct)
    wf[ct] = *(const short8*)(wsW + woff + ct * 2048);
  for (int i = tid; i < 128 * 128 / 8; i += THREADS)
    *(int4*)(sA + i * 8) = make_int4(0, 0, 0, 0);
  if (tid < PPB * 3) sX[tid] = x[p0 * 3 + tid];

  int iraw = iterp[0];
  float it = (iraw > 0 && iraw < 100000000) ? (float)iraw : ((const float*)iterp)[0];
  const float aM = 6.0f * it / 3000.0f;
  __syncthreads();

  // posenc (HW sin/cos in revolutions): value rows + matching tangent entries
  if (tid < PPB * 3) {
    int p = tid / 3, a = tid - p * 3;
    swrite(sA, 4 * p, a, sX[p * 3 + a]);
    swrite(sA, 4 * p + 1 + a, a, 1.0f);
  }
  for (int itx = tid; itx < PPB * 18; itx += THREADS) {
    int p = itx / 18, rem = itx - p * 18;
    int a = rem / 6, j = rem - a * 6;
    float e2 = exp2f((float)(j - 3));
    float mj = e2 * 3.14f;
    float t  = fminf(fmaxf(aM - (float)j, 0.0f), 1.0f);
    float wj = (1.0f - __builtin_amdgcn_cosf(t * 0.49974652f)) * 0.5f;
    float rev = sX[p * 3 + a] * (e2 * 0.49974652f);
    float fr  = rev - floorf(rev);
    float sv = __builtin_amdgcn_sinf(fr);
    float cv = __builtin_amdgcn_cosf(fr);
    int r0 = 4 * p, ksin = 3 + a * 12 + j, kcos = ksin + 6;
    swrite(sA, r0, ksin, sv * wj);
    swrite(sA, r0, kcos, cv * wj);
    swrite(sA, r0 + 1 + a, ksin, cv * mj * wj);
    swrite(sA, r0 + 1 + a, kcos, -sv * mj * wj);
  }
  __syncthreads();   // sA(input) ready

  layer_pass<2, true , true >(sA, b_in,        wsW,             wsW + 16384,     wf, n16, quad, wr, wc, woff);
  layer_pass<4, false, true >(sA, bs + 0*128,  wsW + 16384,     wsW + 2*16384,   wf, n16, quad, wr, wc, woff);
  layer_pass<4, false, true >(sA, bs + 1*128,  wsW + 2*16384,   wsW + 3*16384,   wf, n16, quad, wr, wc, woff);
  layer_pass<4, false, true >(sA, bs + 2*128,  wsW + 3*16384,   wsW + 4*16384,   wf, n16, quad, wr, wc, woff);
  layer_pass<4, false, true >(sA, bs + 3*128,  wsW + 4*16384,   wsW + 5*16384,   wf, n16, quad, wr, wc, woff);
  layer_pass<4, false, true >(sA, bs + 4*128,  wsW + 5*16384,   wsW + 6*16384,   wf, n16, quad, wr, wc, woff);
  layer_pass<4, false, false>(sA, bs + 5*128,  wsW + 6*16384,   wsW,             wf, n16, quad, wr, wc, woff);

  // heads via MFMA: A = head weights (16 rows, 6 used) from global, B = acts
  {
    f32x4 hacc[2];
    hacc[0] = (f32x4){0.f, 0.f, 0.f, 0.f};
    hacc[1] = (f32x4){0.f, 0.f, 0.f, 0.f};
    const unsigned short* hw = wsW + HOFF;
    #pragma unroll
    for (int ks = 0; ks < 4; ++ks) {
      const int ch = ((quad + 4 * ks) ^ n16) << 3;
      short8 aw = *(const short8*)(hw + n16 * 128 + quad * 8 + ks * 32);
      #pragma unroll
      for (int rt = 0; rt < 2; ++rt) {
        short8 bx = *(const short8*)(sA + (wv * 32 + rt * 16 + n16) * 128 + ch);
        hacc[rt] = __builtin_amdgcn_mfma_f32_16x16x32_bf16(aw, bx, hacc[rt], 0, 0, 0);
      }
    }
    #pragma unroll
    for (int rt = 0; rt < 2; ++rt) {
      int r = wv * 32 + rt * 16 + n16;
      *(float4*)(sH + r * 16 + quad * 4) =
          make_float4(hacc[rt][0], hacc[rt][1], hacc[rt][2], hacc[rt][3]);
    }
  }
  __syncthreads();   // sH ready

  // SE(3) epilogue + forward-mode Jacobian: 8 points per wave (lane<8)
  if (lane < 8) {
    const int p = wv * 8 + lane;
    const int gp = p0 + p;
    float X[3] = { sX[p*3+0], sX[p*3+1], sX[p*3+2] };
    float w[3], v[3], dw[3][3], dv[3][3];
    const int rb = p * 4;
    #pragma unroll
    for (int i = 0; i < 3; ++i) {
      w[i] = sH[rb * 16 + i]     + bw[i];
      v[i] = sH[rb * 16 + 3 + i] + bv[i];
      #pragma unroll
      for (int d = 0; d < 3; ++d) {
        dw[d][i] = sH[(rb + 1 + d) * 16 + i];
        dv[d][i] = sH[(rb + 1 + d) * 16 + 3 + i];
      }
    }
    float th  = sqrtf(w[0]*w[0] + w[1]*w[1] + w[2]*w[2]);
    float ith = 1.0f / th;
    float u[3]  = { w[0]*ith, w[1]*ith, w[2]*ith };
    float vh[3] = { v[0]*ith, v[1]*ith, v[2]*ith };
    float s = sinf(th), c = cosf(th);
    float C2 = 1.0f - c;
    float ths = th - s;
    float uxx[3]; cross3(u, X, uxx);
    float udx = dot3(u, X);
    float uxv[3]; cross3(u, vh, uxv);
    float udv = dot3(u, vh);
    #pragma unroll
    for (int i = 0; i < 3; ++i) {
      float Rx = X[i] + s * uxx[i] + C2 * (u[i] * udx - X[i]);
      float tt = th * vh[i] + C2 * uxv[i] + ths * (u[i] * udv - vh[i]);
      out[gp*3 + i] = Rx + tt;
    }
    float* Jout = out + (size_t)NPTS * 3 + (size_t)gp * 9;
    #pragma unroll
    for (int d = 0; d < 3; ++d) {
      float dwv[3] = { dw[d][0], dw[d][1], dw[d][2] };
      float dvv[3] = { dv[d][0], dv[d][1], dv[d][2] };
      float dth = dot3(w, dwv) * ith;
      float du[3], dvhv[3];
      #pragma unroll
      for (int i = 0; i < 3; ++i) {
        du[i]   = (dwv[i] - u[i]  * dth) * ith;
        dvhv[i] = (dvv[i] - vh[i] * dth) * ith;
      }
      float ex[3] = { d == 0 ? 1.0f : 0.0f, d == 1 ? 1.0f : 0.0f, d == 2 ? 1.0f : 0.0f };
      float dsv  = c  * dth;
      float dC2  = s  * dth;
      float dths = C2 * dth;
      float duxx[3]; cross3(du, X, duxx);
      float uxe[3];  cross3(u, ex, uxe);
      float dudx = dot3(du, X) + u[d];
      float duxv[3]; cross3(du, vh, duxv);
      float uxdv[3]; cross3(u, dvhv, uxdv);
      float dudv = dot3(du, vh) + dot3(u, dvhv);
      #pragma unroll
      for (int i = 0; i < 3; ++i) {
        float dRx = ex[i] + dsv * uxx[i] + s * (duxx[i] + uxe[i])
                  + dC2 * (u[i] * udx - X[i])
                  + C2 * (du[i] * udx + u[i] * dudx - ex[i]);
        float dt  = dth * vh[i] + th * dvhv[i] + dC2 * uxv[i]
                  + C2 * (duxv[i] + uxdv[i])
                  + dths * (u[i] * udv - vh[i])
                  + ths * (du[i] * udv + u[i] * dudv - dvhv[i]);
        Jout[i * 3 + d] = dRx + dt;
      }
    }
  }
}

extern "C" void kernel_launch(void* const* d_in, const int* in_sizes, int n_in,
                              void* d_out, int out_size, void* d_ws, size_t ws_size,
                              hipStream_t stream) {
  const float* x    = (const float*)d_in[0];
  const float* W_in = (const float*)d_in[1];
  const float* b_in = (const float*)d_in[2];
  const float* Ws   = (const float*)d_in[3];
  const float* bs   = (const float*)d_in[4];
  const float* Ww   = (const float*)d_in[5];
  const float* bw   = (const float*)d_in[6];
  const float* Wv   = (const float*)d_in[7];
  const float* bv   = (const float*)d_in[8];
  const int*   itp  = (const int*)d_in[9];
  unsigned short* wsW = (unsigned short*)d_ws;   // (7*16384 + 2048) bf16

  convert_weights<<<dim3((HOFF + 2048 + 255) / 256), dim3(256), 0, stream>>>(
      W_in, Ws, Ww, Wv, wsW);
  nerfies_mfma<<<dim3(NBLK), dim3(THREADS), 0, stream>>>(
      x, b_in, bs, bw, bv, wsW, itp, (float*)d_out);
}

// Round 5
// 306.787 us; speedup vs baseline: 1.0080x; 1.0080x over previous
//
#include <hip/hip_runtime.h>
#include <math.h>

#define NPTS    131072
#define PPB     32            // points per block (4 waves x 8 points)
#define THREADS 256
#define NBLK    (NPTS / PPB)  // 4096
#define HOFF    (7 * 16384)   // head-weight offset in wsW (bf16 elems)
#define HSZ     (32 * 128)    // head block: 32 rows (6 used), 128 k

typedef __attribute__((ext_vector_type(8)))  short short8;
typedef __attribute__((ext_vector_type(16))) float f32x16;
typedef __attribute__((ext_vector_type(4)))  float f32x4;

__device__ __forceinline__ unsigned short f2bf(float f) {
  unsigned u = __float_as_uint(f);
  unsigned r = (u + 0x7fffu + ((u >> 16) & 1u)) >> 16;
  return (unsigned short)r;
}
#if defined(__has_builtin)
#if __has_builtin(__builtin_amdgcn_cvt_pk_bf16_f32)
#define HAVE_PK_BF16 1
#endif
#endif
__device__ __forceinline__ unsigned pk2(float lo, float hi) {
#ifdef HAVE_PK_BF16
  auto v = __builtin_amdgcn_cvt_pk_bf16_f32(lo, hi);
  unsigned u; __builtin_memcpy(&u, &v, 4); return u;
#else
  return (unsigned)f2bf(lo) | ((unsigned)f2bf(hi) << 16);
#endif
}
__device__ __forceinline__ void gld16(const unsigned short* g, unsigned short* l) {
  __builtin_amdgcn_global_load_lds(
      (const __attribute__((address_space(1))) unsigned int*)(g),
      (__attribute__((address_space(3))) unsigned int*)(l), 16, 0, 0);
}
__device__ __forceinline__ float selmask(unsigned long long m, float a, float f) {
  float r;
  asm("v_cndmask_b32 %0, %1, %2, %3" : "=v"(r) : "v"(f), "v"(a), "s"(m));
  return r;
}
__device__ __forceinline__ void cross3(const float a[3], const float b[3], float o[3]) {
  o[0] = a[1]*b[2] - a[2]*b[1];
  o[1] = a[2]*b[0] - a[0]*b[2];
  o[2] = a[0]*b[1] - a[1]*b[0];
}
__device__ __forceinline__ float dot3(const float a[3], const float b[3]) {
  return a[0]*b[0] + a[1]*b[1] + a[2]*b[2];
}

// ---- weights -> bf16 workspace: 7x[128c][128k] + heads 32x128 (6 used) ----
__global__ void convert_weights(const float* __restrict__ W_in,
                                const float* __restrict__ Ws,
                                const float* __restrict__ Ww,
                                const float* __restrict__ Wv,
                                unsigned short* __restrict__ wsW) {
  int idx = blockIdx.x * 256 + threadIdx.x;
  if (idx >= HOFF + HSZ) return;
  float v;
  if (idx < HOFF) {
    int l = idx >> 14, r = idx & 16383, c = r >> 7, k = r & 127;
    if (l == 0) v = (k < 39) ? W_in[c * 39 + k] : 0.0f;
    else        v = Ws[(l - 1) * 16384 + c * 128 + k];
  } else {
    int r = idx - HOFF, o = r >> 7, k = r & 127;
    v = (o < 3) ? Ww[o * 128 + k] : (o < 6) ? Wv[(o - 3) * 128 + k] : 0.0f;
  }
  wsW[idx] = f2bf(v);
}

// DMA one layer's weights (32 KB) into an LDS slot, XOR-chunk-swizzled:
// LDS[c][ch16] holds weights[c][k-chunk ch^(c&15)] so reads spread banks.
__device__ __forceinline__ void dma_weights(const unsigned short* __restrict__ g,
                                            unsigned short* lds, int wv, int lane) {
  #pragma unroll
  for (int i = 0; i < 8; ++i) {
    int blk = wv * 8 + i;                 // 1 KB block = 4 rows
    int c   = blk * 4 + (lane >> 4);
    int ch  = (lane & 15) ^ (c & 15);
    gld16(g + c * 128 + ch * 8, lds + blk * 512);
  }
}

// Build next-layer B-frag (8 bf16, k = 16*ks + 8h + j) from packed act regs.
__device__ __forceinline__ short8 bfrag_from_preg(const unsigned (&preg)[32],
                                                  int ks, int h) {
  const int pb = 8 * (ks >> 1) + 4 * (ks & 1);
  unsigned s0 = __shfl_xor(preg[pb + 0], 32, 64);
  unsigned s1 = __shfl_xor(preg[pb + 1], 32, 64);
  unsigned s2 = __shfl_xor(preg[pb + 2], 32, 64);
  unsigned s3 = __shfl_xor(preg[pb + 3], 32, 64);
  unsigned bf[4];
  bf[0] = h ? s2 : preg[pb + 0];
  bf[1] = h ? s3 : preg[pb + 1];
  bf[2] = h ? preg[pb + 2] : s0;
  bf[3] = h ? preg[pb + 3] : s1;
  short8 r; __builtin_memcpy(&r, bf, 16); return r;
}

// One MLP layer: acc[mt] (32 cols each) = W x acts; acts stay in preg.
template <int NKS, bool LEAKY>
__device__ __forceinline__ void mlp_layer(unsigned (&preg)[32],
                                          const unsigned short* __restrict__ sWs,
                                          const float* __restrict__ bg,
                                          int c32, int h, int lane) {
  const bool isv = (lane & 3) == 0;   // row r = lane&31; value rows r%4==0
  f32x16 acc[4];
  // bias folded into acc init (value rows only)
  #pragma unroll
  for (int mt = 0; mt < 4; ++mt)
    #pragma unroll
    for (int q = 0; q < 4; ++q) {
      float4 bb = *(const float4*)(bg + mt * 32 + q * 8 + 4 * h);
      acc[mt][q*4+0] = isv ? bb.x : 0.0f;
      acc[mt][q*4+1] = isv ? bb.y : 0.0f;
      acc[mt][q*4+2] = isv ? bb.z : 0.0f;
      acc[mt][q*4+3] = isv ? bb.w : 0.0f;
    }

  #pragma unroll
  for (int ks = 0; ks < NKS; ++ks) {
    short8 bfrag = bfrag_from_preg(preg, ks, h);
    #pragma unroll
    for (int mt = 0; mt < 4; ++mt) {
      int ch = (2 * ks + h) ^ (c32 & 15);
      short8 afrag = *(const short8*)(sWs + (mt * 32 + c32) * 128 + ch * 8);
      acc[mt] = __builtin_amdgcn_mfma_f32_32x32x16_bf16(afrag, bfrag, acc[mt], 0, 0, 0);
    }
  }

  // activation (mask from value lane of each 4-lane group) + repack to preg
  #pragma unroll
  for (int mt = 0; mt < 4; ++mt)
    #pragma unroll
    for (int q = 0; q < 4; ++q) {
      float pr[4];
      #pragma unroll
      for (int e2 = 0; e2 < 4; ++e2) {
        float post = acc[mt][q * 4 + e2];
        unsigned long long m =
            (__ballot(post > 0.0f) & 0x1111111111111111ULL) * 15ULL;
        pr[e2] = selmask(m, post, LEAKY ? post * 0.01f : 0.0f);
      }
      preg[mt * 8 + 2 * q]     = pk2(pr[0], pr[1]);
      preg[mt * 8 + 2 * q + 1] = pk2(pr[2], pr[3]);
    }
}

__global__ __launch_bounds__(THREADS, 2)
void nerfies_mfma(const float* __restrict__ x,
                  const float* __restrict__ b_in,
                  const float* __restrict__ bs,
                  const float* __restrict__ bw,
                  const float* __restrict__ bv,
                  const unsigned short* __restrict__ wsW,
                  const int* __restrict__ iterp,
                  float* __restrict__ out)
{
  __shared__ __align__(16) unsigned short sW[2 * 16384];  // 2 weight slots, 64 KB
  __shared__ __align__(16) float sH[128 * 8];             // head outs [row][o]

  const int tid  = threadIdx.x;
  const int lane = tid & 63;
  const int wv   = tid >> 6;
  const int c32  = lane & 31;
  const int h    = lane >> 5;
  const int p0   = blockIdx.x * PPB;

  // prologue: DMA layer-0 weights into slot 0 (cover = posenc below)
  dma_weights(wsW, sW, wv, lane);

  // this lane's row: r_local = c32, point = wv*8 + (c32>>2), tangent d = c32&3
  const int rl = c32;
  const int pl = rl >> 2;
  const int d  = rl & 3;
  const int gp = p0 + wv * 8 + pl;
  float X[3] = { x[gp * 3 + 0], x[gp * 3 + 1], x[gp * 3 + 2] };

  int iraw = iterp[0];
  float it = (iraw > 0 && iraw < 100000000) ? (float)iraw : ((const float*)iterp)[0];
  const float aM = 6.0f * it / 3000.0f;

  // ---- posenc directly into packed act registers ----
  // lane owns cols c = 8*cb + 4h + ci (ci 0..3, cb 0..4) of its row
  unsigned preg[32];
  #pragma unroll
  for (int i = 0; i < 32; ++i) preg[i] = 0;
  #pragma unroll
  for (int cb = 0; cb < 5; ++cb) {
    float vp[4];
    #pragma unroll
    for (int ci = 0; ci < 4; ++ci) {
      int c = cb * 8 + 4 * h + ci;
      float val = 0.0f;
      if (c < 3) {
        val = (d == 0) ? X[c] : ((c == d - 1) ? 1.0f : 0.0f);
      } else if (c < 39) {
        int kk = c - 3;
        int a  = kk / 12;
        int rm = kk - a * 12;
        int t  = rm / 6;
        int j  = rm - t * 6;
        float e2 = exp2f((float)(j - 3));
        float mj = e2 * 3.14f;
        float tt = fminf(fmaxf(aM - (float)j, 0.0f), 1.0f);
        float wj = (1.0f - __builtin_amdgcn_cosf(tt * 0.49974652f)) * 0.5f;
        float rev = X[a] * (e2 * 0.49974652f);
        float fr  = rev - floorf(rev);
        float sv = __builtin_amdgcn_sinf(fr);
        float cv = __builtin_amdgcn_cosf(fr);
        if (d == 0)          val = (t == 0 ? sv : cv) * wj;
        else if (a == d - 1) val = (t == 0 ? cv : -sv) * (mj * wj);
      }
      vp[ci] = val;
    }
    int mt = (cb >= 4) ? 1 : 0;
    int pidx = mt * 8 + 2 * (cb & 3);
    preg[pidx]     = pk2(vp[0], vp[1]);
    preg[pidx + 1] = pk2(vp[2], vp[3]);
  }

  // ---- 7 layers; weight slot ring with one-layer-ahead DMA ----
  __syncthreads();                                   // slot0 landed (all waves)
  dma_weights(wsW + 1 * 16384, sW + 16384, wv, lane);
  mlp_layer<3, true >(preg, sW,          b_in,       c32, h, lane);
  __syncthreads();
  dma_weights(wsW + 2 * 16384, sW,         wv, lane);
  mlp_layer<8, false>(preg, sW + 16384, bs + 0*128, c32, h, lane);
  __syncthreads();
  dma_weights(wsW + 3 * 16384, sW + 16384, wv, lane);
  mlp_layer<8, false>(preg, sW,         bs + 1*128, c32, h, lane);
  __syncthreads();
  dma_weights(wsW + 4 * 16384, sW,         wv, lane);
  mlp_layer<8, false>(preg, sW + 16384, bs + 2*128, c32, h, lane);
  __syncthreads();
  dma_weights(wsW + 5 * 16384, sW + 16384, wv, lane);
  mlp_layer<8, false>(preg, sW,         bs + 3*128, c32, h, lane);
  __syncthreads();
  dma_weights(wsW + 6 * 16384, sW,         wv, lane);
  mlp_layer<8, false>(preg, sW + 16384, bs + 4*128, c32, h, lane);
  __syncthreads();
  mlp_layer<8, false>(preg, sW,         bs + 5*128, c32, h, lane);

  // ---- heads: A = head weights (rows o, 6 of 32 used) straight from L2 ----
  {
    f32x16 hacc;
    #pragma unroll
    for (int e = 0; e < 16; ++e) hacc[e] = 0.0f;
    const unsigned short* hw = wsW + HOFF;
    #pragma unroll
    for (int ks = 0; ks < 8; ++ks) {
      short8 bfrag = bfrag_from_preg(preg, ks, h);
      short8 afrag = *(const short8*)(hw + c32 * 128 + ks * 16 + 8 * h);
      hacc = __builtin_amdgcn_mfma_f32_32x32x16_bf16(afrag, bfrag, hacc, 0, 0, 0);
    }
    int rg = wv * 32 + rl;
    if (h == 0) {   // regs 0..3 = outs o=0..3
      *(float4*)(sH + rg * 8) = make_float4(hacc[0], hacc[1], hacc[2], hacc[3]);
    } else {        // regs 0..1 = outs o=4,5
      *(float2*)(sH + rg * 8 + 4) = make_float2(hacc[0], hacc[1]);
    }
  }
  __syncthreads();

  // ---- SE(3) epilogue + forward-mode Jacobian: 8 points per wave ----
  if (lane < 8) {
    const int p  = wv * 8 + lane;
    const int gpp = p0 + p;
    float XX[3] = { x[gpp*3+0], x[gpp*3+1], x[gpp*3+2] };
    float w[3], v[3], dw[3][3], dv[3][3];
    const int rb = p * 4;
    #pragma unroll
    for (int i = 0; i < 3; ++i) {
      w[i] = sH[rb * 8 + i]     + bw[i];
      v[i] = sH[rb * 8 + 3 + i] + bv[i];
      #pragma unroll
      for (int dd = 0; dd < 3; ++dd) {
        dw[dd][i] = sH[(rb + 1 + dd) * 8 + i];
        dv[dd][i] = sH[(rb + 1 + dd) * 8 + 3 + i];
      }
    }
    float th  = sqrtf(w[0]*w[0] + w[1]*w[1] + w[2]*w[2]);
    float ith = 1.0f / th;
    float u[3]  = { w[0]*ith, w[1]*ith, w[2]*ith };
    float vh[3] = { v[0]*ith, v[1]*ith, v[2]*ith };
    float s = sinf(th), c = cosf(th);
    float C2 = 1.0f - c;
    float ths = th - s;
    float uxx[3]; cross3(u, XX, uxx);
    float udx = dot3(u, XX);
    float uxv[3]; cross3(u, vh, uxv);
    float udv = dot3(u, vh);
    #pragma unroll
    for (int i = 0; i < 3; ++i) {
      float Rx = XX[i] + s * uxx[i] + C2 * (u[i] * udx - XX[i]);
      float tt = th * vh[i] + C2 * uxv[i] + ths * (u[i] * udv - vh[i]);
      out[gpp*3 + i] = Rx + tt;
    }
    float* Jout = out + (size_t)NPTS * 3 + (size_t)gpp * 9;
    #pragma unroll
    for (int dd = 0; dd < 3; ++dd) {
      float dwv[3] = { dw[dd][0], dw[dd][1], dw[dd][2] };
      float dvv[3] = { dv[dd][0], dv[dd][1], dv[dd][2] };
      float dth = dot3(w, dwv) * ith;
      float du[3], dvhv[3];
      #pragma unroll
      for (int i = 0; i < 3; ++i) {
        du[i]   = (dwv[i] - u[i]  * dth) * ith;
        dvhv[i] = (dvv[i] - vh[i] * dth) * ith;
      }
      float ex[3] = { dd == 0 ? 1.0f : 0.0f, dd == 1 ? 1.0f : 0.0f, dd == 2 ? 1.0f : 0.0f };
      float dsv  = c  * dth;
      float dC2  = s  * dth;
      float dths = C2 * dth;
      float duxx[3]; cross3(du, XX, duxx);
      float uxe[3];  cross3(u, ex, uxe);
      float dudx = dot3(du, XX) + u[dd];
      float duxv[3]; cross3(du, vh, duxv);
      float uxdv[3]; cross3(u, dvhv, uxdv);
      float dudv = dot3(du, vh) + dot3(u, dvhv);
      #pragma unroll
      for (int i = 0; i < 3; ++i) {
        float dRx = ex[i] + dsv * uxx[i] + s * (duxx[i] + uxe[i])
                  + dC2 * (u[i] * udx - XX[i])
                  + C2 * (du[i] * udx + u[i] * dudx - ex[i]);
        float dt  = dth * vh[i] + th * dvhv[i] + dC2 * uxv[i]
                  + C2 * (duxv[i] + uxdv[i])
                  + dths * (u[i] * udv - vh[i])
                  + ths * (du[i] * udv + u[i] * dudv - dvhv[i]);
        Jout[i * 3 + dd] = dRx + dt;
      }
    }
  }
}

extern "C" void kernel_launch(void* const* d_in, const int* in_sizes, int n_in,
                              void* d_out, int out_size, void* d_ws, size_t ws_size,
                              hipStream_t stream) {
  const float* x    = (const float*)d_in[0];
  const float* W_in = (const float*)d_in[1];
  const float* b_in = (const float*)d_in[2];
  const float* Ws   = (const float*)d_in[3];
  const float* bs   = (const float*)d_in[4];
  const float* Ww   = (const float*)d_in[5];
  const float* bw   = (const float*)d_in[6];
  const float* Wv   = (const float*)d_in[7];
  const float* bv   = (const float*)d_in[8];
  const int*   itp  = (const int*)d_in[9];
  unsigned short* wsW = (unsigned short*)d_ws;   // (7*16384 + 4096) bf16

  convert_weights<<<dim3((HOFF + HSZ + 255) / 256), dim3(256), 0, stream>>>(
      W_in, Ws, Ww, Wv, wsW);
  nerfies_mfma<<<dim3(NBLK), dim3(THREADS), 0, stream>>>(
      x, b_in, bs, bw, bv, wsW, itp, (float*)d_out);
}